// Round 6
// baseline (1138.998 us; speedup 1.0000x reference)
//
#include <hip/hip_runtime.h>

#define NUSERS 100000
#define NITEMS 50000
#define NNODES 150000
#define NEDGES 4800000

#define PSHIFT 13                 // panel width 8192 rows (2 MB of bf16 h)
#define NPAN   19                 // ceil(150000/8192)
#define RPW    37                 // rows per wave
#define NWAVES 4096               // 1024 blocks * 4 waves
#define PR     (NPAN*RPW)         // 703 keys per wave-rowgroup
#define NKEY   (NWAVES*PR)        // 2,879,488 (exact multiple of 2048)
#define NB     (NKEY/2048)        // 1406 scan blocks
#define CHUNK  16

typedef unsigned int uint32;
typedef unsigned long long u64;

// pack two fp32 -> two bf16 (round-to-nearest-even) in one uint
__device__ inline uint32 pack_bf16(float a, float b) {
    uint32 ua = __float_as_uint(a);
    ua += ((ua >> 16) & 1u) + 0x7FFFu;
    uint32 ub = __float_as_uint(b);
    ub += ((ub >> 16) & 1u) + 0x7FFFu;
    return (ua >> 16) | (ub & 0xFFFF0000u);
}

// -------- row_ptr from sorted COO rows --------
__global__ void build_rowptr(const int* __restrict__ rows,
                             int* __restrict__ rowptr,
                             int n_nodes, int n_edges) {
    int r = blockIdx.x * blockDim.x + threadIdx.x;
    if (r > n_nodes) return;
    int lo = 0, hi = n_edges;
    while (lo < hi) {
        int mid = (lo + hi) >> 1;
        if (rows[mid] < r) lo = mid + 1; else hi = mid;
    }
    rowptr[r] = lo;
}

__global__ void zero_kernel(int* __restrict__ p, int n) {
    int i = blockIdx.x * blockDim.x + threadIdx.x;
    int stride = gridDim.x * blockDim.x;
    for (; i < n; i += stride) p[i] = 0;
}

// -------- per-(row,panel) counts into ptr2 (scanned in place later) --------
__global__ void count_kernel(const int* __restrict__ cols,
                             const int* __restrict__ rowptr,
                             int* __restrict__ ptr2) {
    int w = (int)((blockIdx.x * blockDim.x + threadIdx.x) >> 6);
    int lane = threadIdx.x & 63;
    if (w >= NNODES) return;
    int lo = __builtin_amdgcn_readfirstlane(rowptr[w]);
    int hi = __builtin_amdgcn_readfirstlane(rowptr[w + 1]);
    int cnt = 0;
    for (int b = lo; b < hi; b += 64) {
        int e = b + lane; int p = -1;
        if (e < hi) p = cols[e] >> PSHIFT;
        #pragma unroll
        for (int pp = 0; pp < NPAN; ++pp) {
            u64 m = __ballot(p == pp);
            if (lane == pp) cnt += __popcll(m);
        }
    }
    if (lane < NPAN) {
        int rg = w / RPW, rl = w - rg * RPW;
        ptr2[rg * PR + lane * RPW + rl] = cnt;
    }
}

// -------- 3-phase exclusive scan of ptr2[0..NKEY) (in place) --------
__global__ void scan1(int* __restrict__ ptr2, int* __restrict__ bsum) {
    __shared__ int sd[256];
    int tid = threadIdx.x;
    int base = blockIdx.x * 2048 + tid * 8;
    int v[8];
    #pragma unroll
    for (int j = 0; j < 8; ++j) v[j] = ptr2[base + j];
    int t = 0;
    #pragma unroll
    for (int j = 0; j < 8; ++j) { int x = v[j]; v[j] = t; t += x; }
    sd[tid] = t; __syncthreads();
    for (int off = 1; off < 256; off <<= 1) {
        int x = (tid >= off) ? sd[tid - off] : 0;
        __syncthreads();
        sd[tid] += x;
        __syncthreads();
    }
    int texc = sd[tid] - t;
    #pragma unroll
    for (int j = 0; j < 8; ++j) ptr2[base + j] = v[j] + texc;
    if (tid == 255) bsum[blockIdx.x] = sd[255];
}

__global__ void scan2(int* __restrict__ bsum) {
    __shared__ int sd[256];
    int tid = threadIdx.x;
    int running = 0;
    for (int base = 0; base < NB; base += 256) {
        int i = base + tid;
        int v = (i < NB) ? bsum[i] : 0;
        sd[tid] = v; __syncthreads();
        for (int off = 1; off < 256; off <<= 1) {
            int x = (tid >= off) ? sd[tid - off] : 0;
            __syncthreads();
            sd[tid] += x;
            __syncthreads();
        }
        if (i < NB) bsum[i] = sd[tid] - v + running;
        running += sd[255];
        __syncthreads();
    }
}

__global__ void scan3(int* __restrict__ ptr2, const int* __restrict__ bsum) {
    if (blockIdx.x == 0 && threadIdx.x == 0) ptr2[NKEY] = NEDGES;
    int i = blockIdx.x * blockDim.x + threadIdx.x;
    int stride = gridDim.x * blockDim.x;
    for (; i < NKEY; i += stride) ptr2[i] += bsum[i >> 11];
}

// -------- scatter edges into (rowgroup, panel, row)-bucketed order --------
__global__ void scatter_kernel(const int* __restrict__ cols,
                               const float* __restrict__ vals,
                               const int* __restrict__ rowptr,
                               const int* __restrict__ ptr2,
                               int* __restrict__ cols2,     // (lrow<<18)|col
                               float* __restrict__ vals2) {
    int w = (int)((blockIdx.x * blockDim.x + threadIdx.x) >> 6);
    int lane = threadIdx.x & 63;
    if (w >= NNODES) return;
    int lo = __builtin_amdgcn_readfirstlane(rowptr[w]);
    int hi = __builtin_amdgcn_readfirstlane(rowptr[w + 1]);
    int rg = w / RPW, rl = w - rg * RPW;
    int cur = 0;
    if (lane < NPAN) cur = ptr2[rg * PR + lane * RPW + rl];
    for (int b = lo; b < hi; b += 64) {
        int e = b + lane; int p = -1, c = 0; float v = 0.f;
        if (e < hi) { c = cols[e]; v = vals[e]; p = c >> PSHIFT; }
        u64 mym = 0; int add = 0;
        #pragma unroll
        for (int pp = 0; pp < NPAN; ++pp) {
            u64 m = __ballot(p == pp);
            if (p == pp) mym = m;
            if (lane == pp) add = __popcll(m);
        }
        int basec = __shfl(cur, (p < 0) ? 0 : p);
        if (e < hi) {
            int rank = __popcll(mym & ((1ull << lane) - 1ull));
            int pos = basec + rank;
            cols2[pos] = (rl << 18) | c;
            vals2[pos] = v;
        }
        cur += add;
    }
}

// -------- init: hA(bf16) = concat(user,item) --------
__global__ void init_kernel(const float4* __restrict__ ue,
                            const float4* __restrict__ ie,
                            uint2* __restrict__ h,
                            int n_user4, int n_total4) {
    int i = blockIdx.x * blockDim.x + threadIdx.x;
    if (i >= n_total4) return;
    float4 v = (i < n_user4) ? ue[i] : ie[i - n_user4];
    h[i] = make_uint2(pack_bf16(v.x, v.y), pack_bf16(v.z, v.w));
}

// -------- panel-phased SpMM, register accumulators --------
template<int LAST>
__global__ __launch_bounds__(256, 4)
void spmm_panel(const uint32* __restrict__ hsrc,
                uint32* __restrict__ hdst,
                const uint32* __restrict__ hmid,
                const float* __restrict__ ue,
                const float* __restrict__ ie,
                float* __restrict__ out,
                const int* __restrict__ cols2,
                const float* __restrict__ vals2,
                const int* __restrict__ ptr2) {
    __shared__ float2 stage[4][CHUNK][64];   // 32 KB/block
    int wv = threadIdx.x >> 6;               // wave slot for LDS (keep divergent-typed)
    int lane = threadIdx.x & 63;
    int w = __builtin_amdgcn_readfirstlane(blockIdx.x * 4 + wv);  // uniform
    int sbase = w * PR;
    int r0 = w * RPW;

    float ax[RPW], ay[RPW];
    #pragma unroll
    for (int i = 0; i < RPW; ++i) { ax[i] = 0.f; ay[i] = 0.f; }

    #pragma unroll 1
    for (int p = 0; p < NPAN; ++p) {
        int sb = sbase + p * RPW;
        int seg[RPW + 1];
        #pragma unroll
        for (int i = 0; i <= RPW; ++i) seg[i] = ptr2[sb + i];   // uniform -> s_load
        int b0 = seg[0], b1 = seg[RPW];

        #pragma unroll 1
        for (int c0 = b0; c0 < b1; c0 += CHUNK) {
            int cend = min(b1, c0 + CHUNK);
            int pk[CHUNK]; float vv[CHUNK];
            if (c0 + CHUNK <= b1) {
                #pragma unroll
                for (int j = 0; j < CHUNK; ++j) { pk[j] = cols2[c0 + j]; vv[j] = vals2[c0 + j]; }
            } else {
                #pragma unroll
                for (int j = 0; j < CHUNK; ++j) {
                    int e = c0 + j; int idx = (e < cend) ? e : cend - 1;
                    pk[j] = cols2[idx]; vv[j] = (e < cend) ? vals2[idx] : 0.f;
                }
            }
            uint32 g[CHUNK];
            #pragma unroll
            for (int j = 0; j < CHUNK; ++j) {
                uint32 col = ((uint32)pk[j]) & 0x3FFFFu;
                g[j] = hsrc[col * 64u + (uint32)lane];
            }
            #pragma unroll
            for (int j = 0; j < CHUNK; ++j) {
                uint32 u = g[j];
                float hx = __uint_as_float(u << 16);
                float hy = __uint_as_float(u & 0xFFFF0000u);
                stage[wv][j][lane] = make_float2(vv[j] * hx, vv[j] * hy);
            }
            int rmin = pk[0] >> 18;
            int rmax = pk[CHUNK - 1] >> 18;   // padded slots copy last real edge
            #pragma unroll
            for (int ri = 0; ri < RPW; ++ri) {
                if (ri < rmin || ri > rmax) continue;
                int lo = max(seg[ri], c0);
                int hi = min(seg[ri + 1], cend);
                for (int e = lo; e < hi; ++e) {
                    float2 t = stage[wv][e - c0][lane];
                    ax[ri] += t.x; ay[ri] += t.y;
                }
            }
        }
    }

    #pragma unroll
    for (int ri = 0; ri < RPW; ++ri) {
        int row = r0 + ri;
        if (row < NNODES) {
            uint32 off = (uint32)row * 64u + (uint32)lane;
            if (!LAST) {
                hdst[off] = pack_bf16(ax[ri], ay[ri]);
            } else {
                const float* ebase = (row < NUSERS)
                    ? (ue + (size_t)row * 128)
                    : (ie + (size_t)(row - NUSERS) * 128);
                float2 e0 = *reinterpret_cast<const float2*>(ebase + lane * 2);
                uint32 u1 = hmid[off], u2 = hsrc[off];
                float ox = 0.25f * (e0.x + __uint_as_float(u1 << 16)
                                  + __uint_as_float(u2 << 16) + ax[ri]);
                float oy = 0.25f * (e0.y + __uint_as_float(u1 & 0xFFFF0000u)
                                  + __uint_as_float(u2 & 0xFFFF0000u) + ay[ri]);
                *reinterpret_cast<float2*>(out + (size_t)row * 128 + lane * 2)
                    = make_float2(ox, oy);
            }
        }
    }
}

extern "C" void kernel_launch(void* const* d_in, const int* in_sizes, int n_in,
                              void* d_out, int out_size, void* d_ws, size_t ws_size,
                              hipStream_t stream) {
    const float* ue   = (const float*)d_in[0];
    const float* ie   = (const float*)d_in[1];
    const int*   rows = (const int*)  d_in[2];
    const int*   cols = (const int*)  d_in[3];
    const float* vals = (const float*)d_in[4];
    float* out = (float*)d_out;

    // ws layout (all 256B-aligned)
    char* ws = (char*)d_ws;
    size_t o = 0;
    auto carve = [&](size_t bytes) { char* p = ws + o; o = (o + bytes + 255) & ~(size_t)255; return p; };
    int*    rowptr = (int*)   carve((size_t)(NNODES + 1) * 4);
    int*    ptr2   = (int*)   carve((size_t)(NKEY + 1) * 4);
    int*    bsum   = (int*)   carve((size_t)NB * 4);
    int*    cols2  = (int*)   carve((size_t)NEDGES * 4);
    float*  vals2  = (float*) carve((size_t)NEDGES * 4);
    uint32* hA     = (uint32*)carve((size_t)NNODES * 64 * 4);
    uint32* hB     = (uint32*)carve((size_t)NNODES * 64 * 4);

    int rowWaveBlocks = (NNODES * 64 + 255) / 256;

    // 1. rowptr
    build_rowptr<<<(NNODES + 1 + 255) / 256, 256, 0, stream>>>(rows, rowptr, NNODES, NEDGES);
    // 2. bucket preprocessing: counts -> scan -> scatter
    zero_kernel<<<2048, 256, 0, stream>>>(ptr2, NKEY);
    count_kernel<<<rowWaveBlocks, 256, 0, stream>>>(cols, rowptr, ptr2);
    scan1<<<NB, 256, 0, stream>>>(ptr2, bsum);
    scan2<<<1, 256, 0, stream>>>(bsum);
    scan3<<<2048, 256, 0, stream>>>(ptr2, bsum);
    scatter_kernel<<<rowWaveBlocks, 256, 0, stream>>>(cols, vals, rowptr, ptr2, cols2, vals2);
    // 3. init hA = bf16(embeddings)
    init_kernel<<<(NNODES * 32 + 255) / 256, 256, 0, stream>>>(
        (const float4*)ue, (const float4*)ie, (uint2*)hA, NUSERS * 32, NNODES * 32);
    // 4. three panel-phased SpMM layers
    spmm_panel<0><<<1024, 256, 0, stream>>>(hA, hB, nullptr, ue, ie, out, cols2, vals2, ptr2);
    spmm_panel<0><<<1024, 256, 0, stream>>>(hB, hA, nullptr, ue, ie, out, cols2, vals2, ptr2);
    spmm_panel<1><<<1024, 256, 0, stream>>>(hA, nullptr, hB, ue, ie, out, cols2, vals2, ptr2);
}